// Round 18
// baseline (2450.307 us; speedup 1.0000x reference)
//
#include <hip/hip_runtime.h>

typedef unsigned int uint;
typedef unsigned short ushort;
typedef _Float16 f16;
typedef _Float16 f16x2 __attribute__((ext_vector_type(2)));
typedef _Float16 f16x8 __attribute__((ext_vector_type(8)));
typedef float f32x4 __attribute__((ext_vector_type(4)));

#define N_TYPES 10000
#define HID 256
#define G4 1024
#define BATCH 32
#define SEQ 1024
#define NV 100   // weight pairs per row held in VGPRs
#define NL 7     // uint4 groups (4 pairs each) per row held in LDS: 28 pairs

// ---------------- K1: path table: path[n][h] = sum_d cumw_d * emb[anc[n,d]][h]
__global__ void k_path(const int* __restrict__ anc, const float* __restrict__ weight,
                       const float* __restrict__ emb, int D, f16* __restrict__ path) {
  int n = blockIdx.x;
  int h = threadIdx.x;
  float acc = 0.f, cw = 1.f;
  for (int d = 0; d < D; ++d) {
    int a = anc[n * D + d];
    if (a < 0) break;
    acc += cw * emb[a * HID + h];
    cw *= weight[a];
  }
  path[n * HID + h] = (f16)acc;
}

// ---------------- K0: convert W_ih -> f16, W_hh -> transposed packed f16 pairs, bias = b_ih+b_hh
// whh_t layout: [128 kpair][1024 row] u32 (pair = f16 k, k+1 of row)
__global__ void k_conv(const float* __restrict__ wih, const float* __restrict__ whh,
                       const float* __restrict__ bih, const float* __restrict__ bhh,
                       f16* __restrict__ wih_h, uint* __restrict__ whh_t,
                       float* __restrict__ bias) {
  int i = blockIdx.x * 256 + threadIdx.x;   // 262144 threads
  wih_h[i] = (f16)wih[i];
  if (i < G4 * 128) {
    int row = i >> 7, p = i & 127;
    f16x2 v;
    v.x = (f16)whh[row * HID + 2 * p];
    v.y = (f16)whh[row * HID + 2 * p + 1];
    whh_t[p * G4 + row] = __builtin_bit_cast(uint, v);
  }
  if (i < G4) bias[i] = bih[i] + bhh[i];
}

// ---------------- K2: proj[n][dim][gate] = path[n]@W_ih^T + b (gate-packed epilogue)
#define BM 128
#define BN 128
#define BK 64
#define LPAD 72
__global__ __launch_bounds__(256) void k_gemm(const f16* __restrict__ A,
                                              const f16* __restrict__ Bw,
                                              const float* __restrict__ bias,
                                              f16* __restrict__ C) {
  __shared__ f16 sA[BM][LPAD];
  __shared__ f16 sB[BN][LPAD];
  int m0 = blockIdx.x * BM, n0 = blockIdx.y * BN;
  int tid = threadIdx.x;
  int wid = tid >> 6, lane = tid & 63;
  int wm = wid & 1, wn = wid >> 1;
  f32x4 acc[4][4] = {};
  for (int k0 = 0; k0 < 256; k0 += BK) {
    __syncthreads();
    int r = tid >> 3, kc = (tid & 7) * 8;
    for (int i = 0; i < 4; ++i) {
      int row = r + 32 * i;
      int gm = m0 + row;
      uint4 va = make_uint4(0u, 0u, 0u, 0u);
      if (gm < N_TYPES) va = *(const uint4*)&A[gm * 256 + k0 + kc];
      *(uint4*)&sA[row][kc] = va;
      uint4 vb = *(const uint4*)&Bw[(n0 + row) * 256 + k0 + kc];
      *(uint4*)&sB[row][kc] = vb;
    }
    __syncthreads();
#pragma unroll
    for (int ks = 0; ks < 2; ++ks) {
      f16x8 af[4], bf[4];
      int kk = ks * 32 + (lane >> 4) * 8;
#pragma unroll
      for (int mt = 0; mt < 4; ++mt)
        af[mt] = *(const f16x8*)&sA[wm * 64 + mt * 16 + (lane & 15)][kk];
#pragma unroll
      for (int nt = 0; nt < 4; ++nt)
        bf[nt] = *(const f16x8*)&sB[wn * 64 + nt * 16 + (lane & 15)][kk];
#pragma unroll
      for (int mt = 0; mt < 4; ++mt)
#pragma unroll
        for (int nt = 0; nt < 4; ++nt)
          acc[mt][nt] = __builtin_amdgcn_mfma_f32_16x16x32_f16(af[mt], bf[nt], acc[mt][nt], 0, 0, 0);
    }
  }
#pragma unroll
  for (int mt = 0; mt < 4; ++mt)
#pragma unroll
    for (int nt = 0; nt < 4; ++nt)
#pragma unroll
      for (int qq = 0; qq < 4; ++qq) {
        int row = m0 + wm * 64 + mt * 16 + (lane >> 4) * 4 + qq;
        int col = n0 + wn * 64 + nt * 16 + (lane & 15);
        int dim = col & 255, g = col >> 8;
        if (row < N_TYPES)
          C[row * G4 + dim * 4 + g] = (f16)(acc[mt][nt][qq] + bias[col]);
      }
}

// ---------------- K3: LSTM recurrence, v18 = SINGLE-CU PER BATCH (no cross-WG sync).
// R5-R17 post-mortems: 13 variants plateau at 1563-1790us; the binding term is the
// cross-CU agent-fabric handoff RTT (~2500cy/step), untouchable by poll cadence,
// barriers, weight supply, publish ops, or wave roles. This design removes it:
// 32 WGs x 512 threads, one batch per WG per CU. All sync = __syncthreads.
//
// Weight capacity (the reason this was never tried): W_hh packed = 512 KB/batch.
// Register file = 512 KB/CU; R17 proved amdgpu_waves_per_eu reliably unlocks the
// RA budget (VGPR 32->88 there). Here: 8 waves/WG = 2/SIMD -> 256-VGPR budget.
// Thread t owns FULL-K for rows t and 512+t: 100 pairs/row in VGPR (w0,w1 = 200
// VGPRs), 28 pairs/row in LDS (112 KB, per-lane b128 stride-1 = conflict-free).
// h broadcast via wave-uniform uint4 LDS reads (broadcast = no conflict).
// Per-step vmem (out-store of PREVIOUS step + x-gather) issues in phase 0, before
// the matvec, so barrier-A's vmcnt drain finds it retired (R14 ack lesson).
__device__ __forceinline__ float dot2(uint wp, uint hp, float acc) {
#if __has_builtin(__builtin_amdgcn_fdot2)
  return __builtin_amdgcn_fdot2(__builtin_bit_cast(f16x2, wp),
                                __builtin_bit_cast(f16x2, hp), acc, false);
#else
  f16x2 a = __builtin_bit_cast(f16x2, wp);
  f16x2 b = __builtin_bit_cast(f16x2, hp);
  return acc + (float)a.x * (float)b.x + (float)a.y * (float)b.y;
#endif
}

__device__ __forceinline__ float sigm(float v) { return 1.f / (1.f + __expf(-v)); }
__device__ __forceinline__ float tanh_(float v) { return 1.f - 2.f / (__expf(2.f * v) + 1.f); }
__device__ __forceinline__ float f16u(ushort u) { return (float)__builtin_bit_cast(f16, u); }

__global__ __launch_bounds__(512)
__attribute__((amdgpu_waves_per_eu(2, 2)))
void k_lstm(const int* __restrict__ evs,
            const f16* __restrict__ proj,
            const uint* __restrict__ whh_t,
            float* __restrict__ out) {
  int b = blockIdx.x;                  // one batch per WG
  int t = threadIdx.x;                 // rows t and 512+t (row = gate*256 + dim)

  __shared__ uint4 wlds4[NL][1024];    // pairs NV..NV+27 for all 1024 rows: 112 KB
  __shared__ float sl[1024];           // per-row sums
  __shared__ uint hl[128];             // h packed f16 pairs

  // ---- one-time staging: LDS weight tail for rows t and 512+t
#pragma unroll
  for (int g = 0; g < NL; ++g) {
    int p = NV + 4 * g;
    uint4 a;
    a.x = whh_t[(p + 0) * G4 + t];
    a.y = whh_t[(p + 1) * G4 + t];
    a.z = whh_t[(p + 2) * G4 + t];
    a.w = whh_t[(p + 3) * G4 + t];
    wlds4[g][t] = a;
    uint4 bb;
    bb.x = whh_t[(p + 0) * G4 + 512 + t];
    bb.y = whh_t[(p + 1) * G4 + 512 + t];
    bb.z = whh_t[(p + 2) * G4 + 512 + t];
    bb.w = whh_t[(p + 3) * G4 + 512 + t];
    wlds4[g][512 + t] = bb;
  }

  // ---- one-time: VGPR weight body (register-resident under waves_per_eu(2,2))
  uint w0[NV], w1[NV];
#pragma unroll
  for (int p = 0; p < NV; ++p) {
    w0[p] = whh_t[p * G4 + t];
    w1[p] = whh_t[p * G4 + 512 + t];
  }

  const int* ev = evs + b * SEQ;
  float c = 0.f, hval_prev = 0.f;

  __syncthreads();                     // staging visible

  for (int step = 0; step < SEQ; ++step) {
    // ---- phase 0: ALL per-step vmem (prev-step out store + this step's x load);
    // issued before the matvec so barrier-A's drain finds the acks retired.
    float x0 = 0.f, x1 = 0.f, x2 = 0.f, x3 = 0.f;
    if (t < 256) {
      if (step > 0) out[((step - 1) * BATCH + b) * HID + t] = hval_prev;
      ushort4 xv = *(const ushort4*)(proj + (long)ev[step] * G4 + t * 4);
      x0 = f16u(xv.x); x1 = f16u(xv.y); x2 = f16u(xv.z); x3 = f16u(xv.w);
    }

    // ---- phase 1: matvec, full K for rows t and 512+t
    float a0 = 0.f, a1 = 0.f;
    if (step > 0) {
      const uint4* hl4 = (const uint4*)hl;
#pragma unroll
      for (int i = 0; i < NV / 4; ++i) {       // pairs 0..NV-1 from VGPRs
        uint4 h4 = hl4[i];                     // wave-uniform -> broadcast read
        a0 = dot2(w0[4 * i + 0], h4.x, a0);
        a0 = dot2(w0[4 * i + 1], h4.y, a0);
        a0 = dot2(w0[4 * i + 2], h4.z, a0);
        a0 = dot2(w0[4 * i + 3], h4.w, a0);
        a1 = dot2(w1[4 * i + 0], h4.x, a1);
        a1 = dot2(w1[4 * i + 1], h4.y, a1);
        a1 = dot2(w1[4 * i + 2], h4.z, a1);
        a1 = dot2(w1[4 * i + 3], h4.w, a1);
      }
#pragma unroll
      for (int g = 0; g < NL; ++g) {           // pairs NV..127 from LDS
        uint4 h4 = hl4[NV / 4 + g];
        uint4 v0 = wlds4[g][t];                // stride-1 lanes: conflict-free
        uint4 v1 = wlds4[g][512 + t];
        a0 = dot2(v0.x, h4.x, a0);
        a0 = dot2(v0.y, h4.y, a0);
        a0 = dot2(v0.z, h4.z, a0);
        a0 = dot2(v0.w, h4.w, a0);
        a1 = dot2(v1.x, h4.x, a1);
        a1 = dot2(v1.y, h4.y, a1);
        a1 = dot2(v1.z, h4.z, a1);
        a1 = dot2(v1.w, h4.w, a1);
      }
    }
    sl[t] = a0;
    sl[512 + t] = a1;
    __syncthreads();                   // [A] all row sums visible

    // ---- phase 2: finale on t<256 (dim t): gates + c/h + pack h to LDS
    if (t < 256) {
      float s0 = sl[t]       + x0;     // gate i
      float s1 = sl[256 + t] + x1;     // gate f
      float s2 = sl[512 + t] + x2;     // gate g
      float s3 = sl[768 + t] + x3;     // gate o
      float iv = sigm(s0), fv = sigm(s1), gv = tanh_(s2), ov = sigm(s3);
      c = fv * c + iv * gv;
      float hval = ov * tanh_(c);
      hval_prev = hval;                // out store deferred to phase 0 next step
      float hn = __shfl_down(hval, 1);
      if ((t & 1) == 0) {
        f16x2 pk; pk.x = (f16)hval; pk.y = (f16)hn;
        hl[t >> 1] = __builtin_bit_cast(uint, pk);
      }
    }
    __syncthreads();                   // [B] h visible for next step's matvec
    // hazards (all intra-WG, barrier-ordered): sl written phase1(s) pre-A, read
    // phase2(s) A..B, rewritten phase1(s+1) post-B. hl written phase2(s) A..B,
    // read phase1(s+1) post-B pre-A(s+1), rewritten phase2(s+1) post-A(s+1).
  }
  if (t < 256) out[((SEQ - 1) * BATCH + b) * HID + t] = hval_prev;
}

extern "C" void kernel_launch(void* const* d_in, const int* in_sizes, int n_in,
                              void* d_out, int out_size, void* d_ws, size_t ws_size,
                              hipStream_t stream) {
  (void)n_in; (void)out_size; (void)ws_size;
  const int* evs = (const int*)d_in[0];
  const int* anc = (const int*)d_in[1];
  const float* weight = (const float*)d_in[2];
  const float* emb = (const float*)d_in[3];
  const float* wih = (const float*)d_in[4];
  const float* whh = (const float*)d_in[5];
  const float* bih = (const float*)d_in[6];
  const float* bhh = (const float*)d_in[7];
  int D = in_sizes[1] / N_TYPES;

  char* ws = (char*)d_ws;
  f16* path = (f16*)(ws);                       // 10000*256*2 = 5,120,000 (dead after k_gemm)
  f16* wih_h = (f16*)(ws + 5242880);            // 524,288
  uint* whh_t = (uint*)(ws + 5767168);          // 524,288
  float* bias = (float*)(ws + 6291456);         // 4,096
  f16* proj = (f16*)(ws + 6295552);             // 10000*1024*2 = 20,480,000 (gate-packed)
  float* out = (float*)d_out;

  k_conv<<<1024, 256, 0, stream>>>(wih, whh, bih, bhh, wih_h, whh_t, bias);
  k_path<<<N_TYPES, 256, 0, stream>>>(anc, weight, emb, D, path);
  k_gemm<<<dim3(79, 8), 256, 0, stream>>>(path, wih_h, bias, proj);
  k_lstm<<<32, 512, 0, stream>>>(evs, proj, whh_t, out);   // one WG per batch
}

// Round 19
// 2035.929 us; speedup vs baseline: 1.2035x; 1.2035x over previous
//
#include <hip/hip_runtime.h>

typedef unsigned int uint;
typedef unsigned short ushort;
typedef _Float16 f16;
typedef _Float16 f16x2 __attribute__((ext_vector_type(2)));
typedef _Float16 f16x8 __attribute__((ext_vector_type(8)));
typedef float f32x4 __attribute__((ext_vector_type(4)));

#define N_TYPES 10000
#define HID 256
#define G4 1024
#define BATCH 32
#define SEQ 1024
#define NV 100   // weight pairs per row held in registers (VGPR/AGPR)
#define NL 7     // uint4 groups (4 pairs) per row in LDS: pairs 100..127

// ---------------- K1: path table: path[n][h] = sum_d cumw_d * emb[anc[n,d]][h]
__global__ void k_path(const int* __restrict__ anc, const float* __restrict__ weight,
                       const float* __restrict__ emb, int D, f16* __restrict__ path) {
  int n = blockIdx.x;
  int h = threadIdx.x;
  float acc = 0.f, cw = 1.f;
  for (int d = 0; d < D; ++d) {
    int a = anc[n * D + d];
    if (a < 0) break;
    acc += cw * emb[a * HID + h];
    cw *= weight[a];
  }
  path[n * HID + h] = (f16)acc;
}

// ---------------- K0: convert W_ih -> f16, W_hh -> transposed packed f16 pairs, bias = b_ih+b_hh
// whh_t layout: [128 kpair][1024 row] u32 (pair = f16 k, k+1 of row)
__global__ void k_conv(const float* __restrict__ wih, const float* __restrict__ whh,
                       const float* __restrict__ bih, const float* __restrict__ bhh,
                       f16* __restrict__ wih_h, uint* __restrict__ whh_t,
                       float* __restrict__ bias) {
  int i = blockIdx.x * 256 + threadIdx.x;   // 262144 threads
  wih_h[i] = (f16)wih[i];
  if (i < G4 * 128) {
    int row = i >> 7, p = i & 127;
    f16x2 v;
    v.x = (f16)whh[row * HID + 2 * p];
    v.y = (f16)whh[row * HID + 2 * p + 1];
    whh_t[p * G4 + row] = __builtin_bit_cast(uint, v);
  }
  if (i < G4) bias[i] = bih[i] + bhh[i];
}

// ---------------- K2: proj[n][dim][gate] = path[n]@W_ih^T + b (gate-packed epilogue)
#define BM 128
#define BN 128
#define BK 64
#define LPAD 72
__global__ __launch_bounds__(256) void k_gemm(const f16* __restrict__ A,
                                              const f16* __restrict__ Bw,
                                              const float* __restrict__ bias,
                                              f16* __restrict__ C) {
  __shared__ f16 sA[BM][LPAD];
  __shared__ f16 sB[BN][LPAD];
  int m0 = blockIdx.x * BM, n0 = blockIdx.y * BN;
  int tid = threadIdx.x;
  int wid = tid >> 6, lane = tid & 63;
  int wm = wid & 1, wn = wid >> 1;
  f32x4 acc[4][4] = {};
  for (int k0 = 0; k0 < 256; k0 += BK) {
    __syncthreads();
    int r = tid >> 3, kc = (tid & 7) * 8;
    for (int i = 0; i < 4; ++i) {
      int row = r + 32 * i;
      int gm = m0 + row;
      uint4 va = make_uint4(0u, 0u, 0u, 0u);
      if (gm < N_TYPES) va = *(const uint4*)&A[gm * 256 + k0 + kc];
      *(uint4*)&sA[row][kc] = va;
      uint4 vb = *(const uint4*)&Bw[(n0 + row) * 256 + k0 + kc];
      *(uint4*)&sB[row][kc] = vb;
    }
    __syncthreads();
#pragma unroll
    for (int ks = 0; ks < 2; ++ks) {
      f16x8 af[4], bf[4];
      int kk = ks * 32 + (lane >> 4) * 8;
#pragma unroll
      for (int mt = 0; mt < 4; ++mt)
        af[mt] = *(const f16x8*)&sA[wm * 64 + mt * 16 + (lane & 15)][kk];
#pragma unroll
      for (int nt = 0; nt < 4; ++nt)
        bf[nt] = *(const f16x8*)&sB[wn * 64 + nt * 16 + (lane & 15)][kk];
#pragma unroll
      for (int mt = 0; mt < 4; ++mt)
#pragma unroll
        for (int nt = 0; nt < 4; ++nt)
          acc[mt][nt] = __builtin_amdgcn_mfma_f32_16x16x32_f16(af[mt], bf[nt], acc[mt][nt], 0, 0, 0);
    }
  }
#pragma unroll
  for (int mt = 0; mt < 4; ++mt)
#pragma unroll
    for (int nt = 0; nt < 4; ++nt)
#pragma unroll
      for (int qq = 0; qq < 4; ++qq) {
        int row = m0 + wm * 64 + mt * 16 + (lane >> 4) * 4 + qq;
        int col = n0 + wn * 64 + nt * 16 + (lane & 15);
        int dim = col & 255, g = col >> 8;
        if (row < N_TYPES)
          C[row * G4 + dim * 4 + g] = (f16)(acc[mt][nt][qq] + bias[col]);
      }
}

// ---------------- K3: LSTM recurrence, v19 = R18 single-CU + READLANE h-broadcast.
// R18 post-mortem: FETCH=31MB proves weights stayed resident (unified VGPR/AGPR);
// the 5625cy/step came from the LDS pipe -- 32 wave-uniform uint4 h-broadcast reads
// + 14 weight-tail reads = 46 b128/thread/step = ~4400cy serialized (VALUBusy 5.7%).
// Fix: h distributed via registers+readlane (R5-R17-proven): each thread reads TWO
// b32 h words (hl[l], hl[64+l]; stride-1, conflict-free), then 128 readlanes feed
// both rows' dot2s. Per-step LDS: 16 ops/thread (~1440cy); VALU: 128 readlane +
// 256 dot2 (~1536-2560cy incl. possible accvgpr reads); pipes overlap.
// All sync remains __syncthreads on ONE CU -- zero cross-CU fabric.
__device__ __forceinline__ float dot2(uint wp, uint hp, float acc) {
#if __has_builtin(__builtin_amdgcn_fdot2)
  return __builtin_amdgcn_fdot2(__builtin_bit_cast(f16x2, wp),
                                __builtin_bit_cast(f16x2, hp), acc, false);
#else
  f16x2 a = __builtin_bit_cast(f16x2, wp);
  f16x2 b = __builtin_bit_cast(f16x2, hp);
  return acc + (float)a.x * (float)b.x + (float)a.y * (float)b.y;
#endif
}

__device__ __forceinline__ float sigm(float v) { return 1.f / (1.f + __expf(-v)); }
__device__ __forceinline__ float tanh_(float v) { return 1.f - 2.f / (__expf(2.f * v) + 1.f); }
__device__ __forceinline__ float f16u(ushort u) { return (float)__builtin_bit_cast(f16, u); }

__global__ __launch_bounds__(512)
__attribute__((amdgpu_waves_per_eu(2, 2)))
void k_lstm(const int* __restrict__ evs,
            const f16* __restrict__ proj,
            const uint* __restrict__ whh_t,
            float* __restrict__ out) {
  int b = blockIdx.x;                  // one batch per WG per CU
  int t = threadIdx.x;                 // owns rows t and 512+t (row = gate*256+dim)
  int l = t & 63;

  __shared__ uint4 wlds4[NL][1024];    // weight pairs NV..127 for all rows: 112 KB
  __shared__ float sl[1024];           // per-row sums
  __shared__ uint hl[128];             // h packed f16 pairs

  // ---- one-time staging: LDS weight tail for rows t and 512+t
#pragma unroll
  for (int g = 0; g < NL; ++g) {
    int p = NV + 4 * g;
    uint4 a;
    a.x = whh_t[(p + 0) * G4 + t];
    a.y = whh_t[(p + 1) * G4 + t];
    a.z = whh_t[(p + 2) * G4 + t];
    a.w = whh_t[(p + 3) * G4 + t];
    wlds4[g][t] = a;
    uint4 bb;
    bb.x = whh_t[(p + 0) * G4 + 512 + t];
    bb.y = whh_t[(p + 1) * G4 + 512 + t];
    bb.z = whh_t[(p + 2) * G4 + 512 + t];
    bb.w = whh_t[(p + 3) * G4 + 512 + t];
    wlds4[g][512 + t] = bb;
  }

  // ---- one-time: register-resident weight body (unified VGPR/AGPR file)
  uint w0[NV], w1[NV];
#pragma unroll
  for (int p = 0; p < NV; ++p) {
    w0[p] = whh_t[p * G4 + t];
    w1[p] = whh_t[p * G4 + 512 + t];
  }

  const int* ev = evs + b * SEQ;
  float c = 0.f, hval_prev = 0.f;

  __syncthreads();                     // staging visible

  for (int step = 0; step < SEQ; ++step) {
    // ---- phase 0: ALL per-step vmem (prev out store + x gather); retires under matvec
    float x0 = 0.f, x1 = 0.f, x2 = 0.f, x3 = 0.f;
    if (t < 256) {
      if (step > 0) out[((step - 1) * BATCH + b) * HID + t] = hval_prev;
      ushort4 xv = *(const ushort4*)(proj + (long)ev[step] * G4 + t * 4);
      x0 = f16u(xv.x); x1 = f16u(xv.y); x2 = f16u(xv.z); x3 = f16u(xv.w);
    }

    // ---- phase 1: matvec, full K for rows t and 512+t; h via registers+readlane
    float a0 = 0.f, a1 = 0.f;
    if (step > 0) {
      int hA = (int)hl[l];             // pair l        (b32, stride-1: conflict-free)
      int hB = (int)hl[64 + l];        // pair 64+l
#pragma unroll
      for (int i = 0; i < 64; ++i) {   // pairs 0..63 from hA, 64..127 from hB
        uint hpA = (uint)__builtin_amdgcn_readlane(hA, i);
        if (i < NV) {
          a0 = dot2(w0[i], hpA, a0);
          a1 = dot2(w1[i], hpA, a1);
        } else {
          int g = (i - NV) >> 2, e = (i - NV) & 3;
          a0 = dot2(((const uint*)&wlds4[g][t])[e], hpA, a0);
          a1 = dot2(((const uint*)&wlds4[g][512 + t])[e], hpA, a1);
        }
        uint hpB = (uint)__builtin_amdgcn_readlane(hB, i);
        int j = 64 + i;
        if (j < NV) {
          a0 = dot2(w0[j], hpB, a0);
          a1 = dot2(w1[j], hpB, a1);
        } else {
          int g = (j - NV) >> 2, e = (j - NV) & 3;
          a0 = dot2(((const uint*)&wlds4[g][t])[e], hpB, a0);
          a1 = dot2(((const uint*)&wlds4[g][512 + t])[e], hpB, a1);
        }
      }
    }
    sl[t] = a0;
    sl[512 + t] = a1;
    __syncthreads();                   // [A] all row sums visible

    // ---- phase 2: finale on t<256 (dim t): gates + c/h + pack h to LDS
    if (t < 256) {
      float s0 = sl[t]       + x0;     // gate i
      float s1 = sl[256 + t] + x1;     // gate f
      float s2 = sl[512 + t] + x2;     // gate g
      float s3 = sl[768 + t] + x3;     // gate o
      float iv = sigm(s0), fv = sigm(s1), gv = tanh_(s2), ov = sigm(s3);
      c = fv * c + iv * gv;
      float hval = ov * tanh_(c);
      hval_prev = hval;                // out store deferred to phase 0 next step
      float hn = __shfl_down(hval, 1);
      if ((t & 1) == 0) {
        f16x2 pk; pk.x = (f16)hval; pk.y = (f16)hn;
        hl[t >> 1] = __builtin_bit_cast(uint, pk);
      }
    }
    __syncthreads();                   // [B] h visible for next step's matvec
    // hazards (intra-WG, barrier-ordered): sl written phase1(s) pre-A, read
    // phase2(s) A..B, rewritten phase1(s+1) post-B. hl read phase1(s) pre-A,
    // written phase2(s) A..B. All safe.
  }
  if (t < 256) out[((SEQ - 1) * BATCH + b) * HID + t] = hval_prev;
}

extern "C" void kernel_launch(void* const* d_in, const int* in_sizes, int n_in,
                              void* d_out, int out_size, void* d_ws, size_t ws_size,
                              hipStream_t stream) {
  (void)n_in; (void)out_size; (void)ws_size;
  const int* evs = (const int*)d_in[0];
  const int* anc = (const int*)d_in[1];
  const float* weight = (const float*)d_in[2];
  const float* emb = (const float*)d_in[3];
  const float* wih = (const float*)d_in[4];
  const float* whh = (const float*)d_in[5];
  const float* bih = (const float*)d_in[6];
  const float* bhh = (const float*)d_in[7];
  int D = in_sizes[1] / N_TYPES;

  char* ws = (char*)d_ws;
  f16* path = (f16*)(ws);                       // 10000*256*2 = 5,120,000 (dead after k_gemm)
  f16* wih_h = (f16*)(ws + 5242880);            // 524,288
  uint* whh_t = (uint*)(ws + 5767168);          // 524,288
  float* bias = (float*)(ws + 6291456);         // 4,096
  f16* proj = (f16*)(ws + 6295552);             // 10000*1024*2 = 20,480,000 (gate-packed)
  float* out = (float*)d_out;

  k_conv<<<1024, 256, 0, stream>>>(wih, whh, bih, bhh, wih_h, whh_t, bias);
  k_path<<<N_TYPES, 256, 0, stream>>>(anc, weight, emb, D, path);
  k_gemm<<<dim3(79, 8), 256, 0, stream>>>(path, wih_h, bias, proj);
  k_lstm<<<32, 512, 0, stream>>>(evs, proj, whh_t, out);   // one WG per batch
}